// Round 8
// baseline (135.055 us; speedup 1.0000x reference)
//
#include <hip/hip_runtime.h>
#include <math.h>

#define NF 1024
#define DIM 256
#define BATCH 2048
#define K 512              // interleaved (x^2, x) -> 2*DIM
#define BMF 16             // batch rows per k_main block
#define NCC 4              // formula chunks
#define CF (NF / NCC)      // 256 formulas per chunk
#define KS 32              // k elems per step
#define NSTEP (K / KS)     // 16
#define NRG (BATCH / BMF)  // 128 row-groups

// ws layout:
//   [0, 1MB)       : Bb bf16 [NCC][NSTEP][4(q)][CF][8]  (step-major: each
//                    lane's per-step fragment is a contiguous 16B dwordx4,
//                    lanes m16=0..15 form contiguous 256B segments)
//   [1MB, +4KB)    : c  float[NF]
//   [1MB+4KB, +32K): rowPartial float[NCC][BATCH]
//   then           : cnt int[NRG]  (zeroed by k_prep each iteration)
#define WS_C_OFF   (NF * K * 2)
#define WS_RP_OFF  (WS_C_OFF + NF * 4)
#define WS_CNT_OFF (WS_RP_OFF + NCC * BATCH * 4)

typedef __attribute__((ext_vector_type(8))) short short8;   // 8 bf16
typedef __attribute__((ext_vector_type(4))) float f32x4;    // MFMA acc

__device__ __forceinline__ unsigned short f2bf(float f) {
    unsigned u = __float_as_uint(f);
    u += 0x7fffu + ((u >> 16) & 1u);       // RNE
    return (unsigned short)(u >> 16);
}

// ---------------------------------------------------------------------------
// K1: 256 blocks x 256 threads. Wave = one formula f; lane sq = (s,q) pair
// handles dims d0 = sq*4 .. +3. Fully-coalesced float4 loads, one uint4
// store into step-major Bb. c[f] via in-wave shuffle reduce.
// Also zeroes cnt[] for k_main's last-block-done protocol.
__global__ __launch_bounds__(256) void k_prep(const float* __restrict__ mu,
                                              const float* __restrict__ sigma,
                                              uint4* __restrict__ Bb4,
                                              float* __restrict__ c,
                                              int* __restrict__ cnt) {
    const int t = threadIdx.x;
    if (blockIdx.x < NRG && t == 0) cnt[blockIdx.x] = 0;

    const int f = blockIdx.x * 4 + (t >> 6);
    const int sq = t & 63;                 // s = sq>>2, q = sq&3
    const float4 mv = *(const float4*)&mu[f * DIM + sq * 4];
    const float4 sv = *(const float4*)&sigma[f * DIM + sq * 4];

    uint4 pk; float cp = 0.f;
    {
        const float s2x = sv.x * sv.x;
        pk.x = (unsigned)f2bf(s2x) | ((unsigned)f2bf(-2.0f * s2x * mv.x) << 16);
        cp += s2x * mv.x * mv.x;
        const float s2y = sv.y * sv.y;
        pk.y = (unsigned)f2bf(s2y) | ((unsigned)f2bf(-2.0f * s2y * mv.y) << 16);
        cp += s2y * mv.y * mv.y;
        const float s2z = sv.z * sv.z;
        pk.z = (unsigned)f2bf(s2z) | ((unsigned)f2bf(-2.0f * s2z * mv.z) << 16);
        cp += s2z * mv.z * mv.z;
        const float s2w = sv.w * sv.w;
        pk.w = (unsigned)f2bf(s2w) | ((unsigned)f2bf(-2.0f * s2w * mv.w) << 16);
        cp += s2w * mv.w * mv.w;
    }
    // uint4 index: cc*16384 + s*1024 + q*256 + fl   (cc = f>>8, fl = f&255)
    Bb4[(f >> 8) * 16384 + (sq >> 2) * 1024 + (sq & 3) * 256 + (f & 255)] = pk;

    #pragma unroll
    for (int off = 32; off > 0; off >>= 1) cp += __shfl_down(cp, off, 64);
    if ((t & 63) == 0) c[f] = cp;
}

// ---------------------------------------------------------------------------
// K2: grid (128 row-groups, 4 chunks) = 512 blocks x 256 threads (4 waves),
// 2 blocks/CU. Block = 16 batch rows x 256 formulas; wave w owns formulas
// [cc*256 + w*64, +64).
//   A (16x512 bf16, 16 KB): packed into XOR-swizzled LDS, shared by all
//     4 waves -> ONE barrier before the K-loop.
//   B: global->reg double-buffered dwordx4 from step-major layout;
//     barrier-free K-loop, TLP hides L2 latency.
//   Normalization fused via last-block-done: after publishing rowPartial,
//     threadfence + atomicAdd(cnt[rg]); the 4th block normalizes the 16
//     rows in place. No k_norm pass, no spin (deadlock-free).
__global__ __launch_bounds__(256, 2) void k_main(const float* __restrict__ x,
                                                 const ushort* __restrict__ Bb,
                                                 const float* __restrict__ c,
                                                 const float* __restrict__ temp,
                                                 float* __restrict__ out,
                                                 float* __restrict__ rowPartial,
                                                 int* __restrict__ cnt) {
    const int t = threadIdx.x;
    const int w = t >> 6;          // wave 0..3
    const int lane = t & 63;
    const int m16 = lane & 15;
    const int q = lane >> 4;       // 0..3
    const int rg = blockIdx.x;
    const int r0 = rg * BMF;
    const int cc = blockIdx.y;

    __shared__ __align__(16) ushort ldsA[BMF * K];      // 16 KB, swizzled
    __shared__ float wsum[4][BMF];
    __shared__ float rowInvS[BMF];
    __shared__ int sLast;

    // ---- pack A: 1024 units of (row, kc-chunk of 4 dims) ----
    #pragma unroll
    for (int h = 0; h < 4; ++h) {
        const int u = h * 256 + t;
        const int row = u >> 6, kc = u & 63;
        const float4 v = *(const float4*)&x[(r0 + row) * DIM + kc * 4];
        uint4 pk;
        pk.x = (unsigned)f2bf(v.x * v.x) | ((unsigned)f2bf(v.x) << 16);
        pk.y = (unsigned)f2bf(v.y * v.y) | ((unsigned)f2bf(v.y) << 16);
        pk.z = (unsigned)f2bf(v.z * v.z) | ((unsigned)f2bf(v.z) << 16);
        pk.w = (unsigned)f2bf(v.w * v.w) | ((unsigned)f2bf(v.w) << 16);
        *(uint4*)&ldsA[(row * 64 + (kc ^ (row & 7))) * 8] = pk;
    }

    f32x4 acc[4];
    #pragma unroll
    for (int ct = 0; ct < 4; ++ct) acc[ct] = (f32x4){0.f, 0.f, 0.f, 0.f};

    // per-lane B pointer: chunk cc, q-slot, formula fl = w*64 + m16;
    // tile ct -> +ct*128 elems; step s -> +s*8192 elems.
    const ushort* bp = Bb + cc * (CF * K) + q * (CF * 8) + (w * 64 + m16) * 8;

    // prologue: step 0 into bA
    short8 bA[4], bB[4];
    #pragma unroll
    for (int ct = 0; ct < 4; ++ct)
        bA[ct] = *(const short8*)(bp + ct * 128);

    __syncthreads();   // ldsA ready

    // ---- K loop: barrier-free, reg double-buffered B ----
    #pragma unroll 1
    for (int s = 0; s < NSTEP; s += 2) {
        #pragma unroll
        for (int ct = 0; ct < 4; ++ct)
            bB[ct] = *(const short8*)(bp + (s + 1) * 8192 + ct * 128);
        {
            const int kcq = s * 4 + q;
            const short8 av = *(const short8*)&ldsA[(m16 * 64 + (kcq ^ (m16 & 7))) * 8];
            #pragma unroll
            for (int ct = 0; ct < 4; ++ct)
                acc[ct] = __builtin_amdgcn_mfma_f32_16x16x32_bf16(av, bA[ct], acc[ct], 0, 0, 0);
        }
        if (s + 2 < NSTEP) {
            #pragma unroll
            for (int ct = 0; ct < 4; ++ct)
                bA[ct] = *(const short8*)(bp + (s + 2) * 8192 + ct * 128);
        }
        {
            const int kcq = (s + 1) * 4 + q;
            const short8 av = *(const short8*)&ldsA[(m16 * 64 + (kcq ^ (m16 & 7))) * 8];
            #pragma unroll
            for (int ct = 0; ct < 4; ++ct)
                acc[ct] = __builtin_amdgcn_mfma_f32_16x16x32_bf16(av, bB[ct], acc[ct], 0, 0, 0);
        }
    }

    // ---- epilogue: p = exp(g*exp(-dist)); store + per-chunk row sums ----
    const float g = 1.0f / (1.0f + __expf(-temp[0]));
    float s4[4] = {0.f, 0.f, 0.f, 0.f};
    #pragma unroll
    for (int ct = 0; ct < 4; ++ct) {
        const int fcol = cc * CF + w * 64 + ct * 16 + m16;
        const float cn = c[fcol];
        #pragma unroll
        for (int i = 0; i < 4; ++i) {
            const float dist2 = acc[ct][i] + cn;
            const float dist = sqrtf(fmaxf(dist2, 0.0f));
            const float p = __expf(g * __expf(-dist));
            out[(r0 + q * 4 + i) * NF + fcol] = p;
            s4[i] += p;
        }
    }
    #pragma unroll
    for (int i = 0; i < 4; ++i) {
        #pragma unroll
        for (int mask = 1; mask < 16; mask <<= 1)
            s4[i] += __shfl_xor(s4[i], mask, 64);
    }
    if (m16 == 0) {
        #pragma unroll
        for (int i = 0; i < 4; ++i) wsum[w][q * 4 + i] = s4[i];
    }
    __syncthreads();
    if (t < BMF)
        rowPartial[cc * BATCH + r0 + t] =
            (wsum[0][t] + wsum[1][t]) + (wsum[2][t] + wsum[3][t]);

    // ---- last-block-done: 4th chunk-block of this rg normalizes rows ----
    __threadfence();                       // release: out + rowPartial visible
    __syncthreads();                       // all lanes' stores fenced
    if (t == 0) sLast = (atomicAdd(&cnt[rg], 1) == NCC - 1);
    __syncthreads();
    if (!sLast) return;

    __threadfence();                       // acquire: see siblings' writes
    if (t < BMF) {
        const int row = r0 + t;
        const float ssum = (rowPartial[row] + rowPartial[BATCH + row]) +
                           (rowPartial[2 * BATCH + row] + rowPartial[3 * BATCH + row]);
        rowInvS[t] = 1.0f / ssum;
    }
    __syncthreads();
    #pragma unroll 1
    for (int row = 0; row < BMF; ++row) {
        const float inv = rowInvS[row];
        float4* o4 = (float4*)(out + (r0 + row) * NF);
        float4 v = o4[t];
        v.x *= inv; v.y *= inv; v.z *= inv; v.w *= inv;
        o4[t] = v;
    }
}

extern "C" void kernel_launch(void* const* d_in, const int* in_sizes, int n_in,
                              void* d_out, int out_size, void* d_ws, size_t ws_size,
                              hipStream_t stream) {
    const float* x     = (const float*)d_in[0];
    const float* mu    = (const float*)d_in[1];
    const float* sigma = (const float*)d_in[2];
    const float* temp  = (const float*)d_in[3];
    float* out = (float*)d_out;

    char* ws = (char*)d_ws;
    ushort* Bb         = (ushort*)ws;
    float*  c          = (float*)(ws + WS_C_OFF);
    float*  rowPartial = (float*)(ws + WS_RP_OFF);
    int*    cnt        = (int*)(ws + WS_CNT_OFF);

    k_prep<<<NF / 4, 256, 0, stream>>>(mu, sigma, (uint4*)Bb, c, cnt);

    dim3 g2(BATCH / BMF, NCC);
    k_main<<<g2, 256, 0, stream>>>(x, Bb, c, temp, out, rowPartial, cnt);
}

// Round 9
// 75.416 us; speedup vs baseline: 1.7908x; 1.7908x over previous
//
#include <hip/hip_runtime.h>
#include <math.h>

#define NF 1024
#define DIM 256
#define BATCH 2048
#define K 512              // interleaved (x^2, x) -> 2*DIM
#define BMF 16             // batch rows per fused block
#define KS 32              // k elems per step
#define NSTEP (K / KS)     // 16

// ws layout:
//   [0, 1MB)    : Bb bf16 [NSTEP][4(q)][NF][8]  (step-major: each lane's
//                 per-step fragment is a contiguous 16B dwordx4; lanes
//                 m16=0..15 form contiguous 256B segments)
//   [1MB, +4KB) : c  float[NF]
#define WS_C_OFF (NF * K * 2)

typedef __attribute__((ext_vector_type(8))) short short8;   // 8 bf16
typedef __attribute__((ext_vector_type(4))) float f32x4;    // MFMA acc

__device__ __forceinline__ unsigned short f2bf(float f) {
    unsigned u = __float_as_uint(f);
    u += 0x7fffu + ((u >> 16) & 1u);       // RNE
    return (unsigned short)(u >> 16);
}

// ---------------------------------------------------------------------------
// K1: 256 blocks x 256 threads. Wave = one formula f; lane sq = (s,q) pair
// handles dims d0 = sq*4 .. +3. Fully-coalesced float4 loads, one uint4
// store into step-major Bb. c[f] via in-wave shuffle reduce.
__global__ __launch_bounds__(256) void k_prep(const float* __restrict__ mu,
                                              const float* __restrict__ sigma,
                                              uint4* __restrict__ Bb4,
                                              float* __restrict__ c) {
    const int t = threadIdx.x;
    const int f = blockIdx.x * 4 + (t >> 6);
    const int sq = t & 63;                 // s = sq>>2, q = sq&3
    const float4 mv = *(const float4*)&mu[f * DIM + sq * 4];
    const float4 sv = *(const float4*)&sigma[f * DIM + sq * 4];

    uint4 pk; float cp = 0.f;
    {
        const float s2x = sv.x * sv.x;
        pk.x = (unsigned)f2bf(s2x) | ((unsigned)f2bf(-2.0f * s2x * mv.x) << 16);
        cp += s2x * mv.x * mv.x;
        const float s2y = sv.y * sv.y;
        pk.y = (unsigned)f2bf(s2y) | ((unsigned)f2bf(-2.0f * s2y * mv.y) << 16);
        cp += s2y * mv.y * mv.y;
        const float s2z = sv.z * sv.z;
        pk.z = (unsigned)f2bf(s2z) | ((unsigned)f2bf(-2.0f * s2z * mv.z) << 16);
        cp += s2z * mv.z * mv.z;
        const float s2w = sv.w * sv.w;
        pk.w = (unsigned)f2bf(s2w) | ((unsigned)f2bf(-2.0f * s2w * mv.w) << 16);
        cp += s2w * mv.w * mv.w;
    }
    // uint4 index: s*4096 + q*1024 + f
    Bb4[(sq >> 2) * 4096 + (sq & 3) * 1024 + f] = pk;

    #pragma unroll
    for (int off = 32; off > 0; off >>= 1) cp += __shfl_down(cp, off, 64);
    if ((t & 63) == 0) c[f] = cp;
}

// ---------------------------------------------------------------------------
// K2: fused GEMM + epilogue + FULL-ROW softmax normalization.
// 128 blocks x 1024 threads (16 waves, 16 waves/CU for TLP). Block = 16
// batch rows x ALL 1024 formulas -> denominator is block-local: p stays in
// registers, out written exactly ONCE (normalized). No k_norm, no fences,
// no cross-block sync of any kind.
//   A (16x512 bf16, 16 KB): XOR-swizzled LDS, shared by all 16 waves.
//   B: global->reg double-buffered dwordx4 from step-major Bb (r7's proven
//      barrier-free pattern); wave w owns formulas [w*64, +64) as 4 ct
//      tiles. K-loop has zero barriers.
__global__ __launch_bounds__(1024, 1) void k_fused(const float* __restrict__ x,
                                                   const ushort* __restrict__ Bb,
                                                   const float* __restrict__ c,
                                                   const float* __restrict__ temp,
                                                   float* __restrict__ out) {
    const int t = threadIdx.x;
    const int w = t >> 6;          // wave 0..15
    const int lane = t & 63;
    const int m16 = lane & 15;
    const int q = lane >> 4;       // 0..3
    const int r0 = blockIdx.x * BMF;

    __shared__ __align__(16) ushort ldsA[BMF * K];      // 16 KB, swizzled
    __shared__ float wsum[16][BMF];
    __shared__ float rowInv[BMF];

    // ---- pack A: 1024 units, one per thread ----
    {
        const int row = t >> 6, kc = t & 63;
        const float4 v = *(const float4*)&x[(r0 + row) * DIM + kc * 4];
        uint4 pk;
        pk.x = (unsigned)f2bf(v.x * v.x) | ((unsigned)f2bf(v.x) << 16);
        pk.y = (unsigned)f2bf(v.y * v.y) | ((unsigned)f2bf(v.y) << 16);
        pk.z = (unsigned)f2bf(v.z * v.z) | ((unsigned)f2bf(v.z) << 16);
        pk.w = (unsigned)f2bf(v.w * v.w) | ((unsigned)f2bf(v.w) << 16);
        *(uint4*)&ldsA[(row * 64 + (kc ^ (row & 7))) * 8] = pk;
    }

    f32x4 acc[4];
    #pragma unroll
    for (int ct = 0; ct < 4; ++ct) acc[ct] = (f32x4){0.f, 0.f, 0.f, 0.f};

    // per-lane B pointer: q-slot, formula fl = w*64 + m16;
    // ct tile -> +ct*128 elems; step s -> +s*32768 elems.
    const ushort* bp = Bb + q * (NF * 8) + (w * 64 + m16) * 8;

    // prologue: step 0 into bA
    short8 bA[4], bB[4];
    #pragma unroll
    for (int ct = 0; ct < 4; ++ct)
        bA[ct] = *(const short8*)(bp + ct * 128);

    __syncthreads();   // ldsA ready (only pre-epilogue barrier)

    // ---- K loop: barrier-free, reg double-buffered B ----
    #pragma unroll 1
    for (int s = 0; s < NSTEP; s += 2) {
        #pragma unroll
        for (int ct = 0; ct < 4; ++ct)
            bB[ct] = *(const short8*)(bp + (s + 1) * (NF * KS) + ct * 128);
        {
            const int kcq = s * 4 + q;
            const short8 av = *(const short8*)&ldsA[(m16 * 64 + (kcq ^ (m16 & 7))) * 8];
            #pragma unroll
            for (int ct = 0; ct < 4; ++ct)
                acc[ct] = __builtin_amdgcn_mfma_f32_16x16x32_bf16(av, bA[ct], acc[ct], 0, 0, 0);
        }
        if (s + 2 < NSTEP) {
            #pragma unroll
            for (int ct = 0; ct < 4; ++ct)
                bA[ct] = *(const short8*)(bp + (s + 2) * (NF * KS) + ct * 128);
        }
        {
            const int kcq = (s + 1) * 4 + q;
            const short8 av = *(const short8*)&ldsA[(m16 * 64 + (kcq ^ (m16 & 7))) * 8];
            #pragma unroll
            for (int ct = 0; ct < 4; ++ct)
                acc[ct] = __builtin_amdgcn_mfma_f32_16x16x32_bf16(av, bB[ct], acc[ct], 0, 0, 0);
        }
    }

    // ---- epilogue: p = exp(g*exp(-dist)) in registers; wave row-sums ----
    const float g = 1.0f / (1.0f + __expf(-temp[0]));
    float s4[4] = {0.f, 0.f, 0.f, 0.f};
    #pragma unroll
    for (int ct = 0; ct < 4; ++ct) {
        const float cn = c[w * 64 + ct * 16 + m16];
        #pragma unroll
        for (int i = 0; i < 4; ++i) {
            const float dist2 = acc[ct][i] + cn;
            const float dist = sqrtf(fmaxf(dist2, 0.0f));
            const float p = __expf(g * __expf(-dist));
            acc[ct][i] = p;
            s4[i] += p;
        }
    }
    #pragma unroll
    for (int i = 0; i < 4; ++i) {
        #pragma unroll
        for (int mask = 1; mask < 16; mask <<= 1)
            s4[i] += __shfl_xor(s4[i], mask, 64);
    }
    if (m16 == 0) {
        #pragma unroll
        for (int i = 0; i < 4; ++i) wsum[w][q * 4 + i] = s4[i];
    }
    __syncthreads();
    if (t < BMF) {
        float ssum = 0.f;
        #pragma unroll
        for (int ww = 0; ww < 16; ++ww) ssum += wsum[ww][t];
        rowInv[t] = 1.0f / ssum;
    }
    __syncthreads();

    // ---- normalize in-register p, single coalesced out write ----
    float inv[4];
    #pragma unroll
    for (int i = 0; i < 4; ++i) inv[i] = rowInv[q * 4 + i];
    #pragma unroll
    for (int ct = 0; ct < 4; ++ct) {
        const int fcol = w * 64 + ct * 16 + m16;
        #pragma unroll
        for (int i = 0; i < 4; ++i)
            out[(r0 + q * 4 + i) * NF + fcol] = acc[ct][i] * inv[i];
    }
}

extern "C" void kernel_launch(void* const* d_in, const int* in_sizes, int n_in,
                              void* d_out, int out_size, void* d_ws, size_t ws_size,
                              hipStream_t stream) {
    const float* x     = (const float*)d_in[0];
    const float* mu    = (const float*)d_in[1];
    const float* sigma = (const float*)d_in[2];
    const float* temp  = (const float*)d_in[3];
    float* out = (float*)d_out;

    char* ws = (char*)d_ws;
    ushort* Bb = (ushort*)ws;
    float*  c  = (float*)(ws + WS_C_OFF);

    k_prep<<<NF / 4, 256, 0, stream>>>(mu, sigma, (uint4*)Bb, c);
    k_fused<<<BATCH / BMF, 1024, 0, stream>>>(x, Bb, c, temp, out);
}